// Round 2
// baseline (1824.564 us; speedup 1.0000x reference)
//
#include <hip/hip_runtime.h>
#include <math.h>

// ---- model constants ----
#define BS_TOT   1024          // B*S
#define DM       256           // d_model
#define DST      128           // d_state
#define TSTEPS   8
#define DECAYF   0.6065306597126334f
#define SCALEF   0.17677669529663689f   // 1/sqrt(32)
#define NE       (BS_TOT * DM)          // 262144

// ======================= embedding =======================
__global__ void embed_k(const int* __restrict__ ids, const float* __restrict__ emb,
                        float* __restrict__ tok) {
    int r = blockIdx.x, c = threadIdx.x;
    tok[r * DM + c] = emb[(size_t)ids[r] * DM + c];
}

// ======================= per-layer init / weight transpose =======================
// grid 1024 x 256 (covers 262144)
__global__ void init_k(float* __restrict__ h, float* __restrict__ sv, float* __restrict__ ov,
                       float* __restrict__ W1T, float* __restrict__ B1,
                       float* __restrict__ WoT, float* __restrict__ CT,
                       const float* __restrict__ Al, const float* __restrict__ Wql,
                       const float* __restrict__ bql, const float* __restrict__ Wol,
                       const float* __restrict__ Cl, int* __restrict__ cnts) {
    int i = blockIdx.x * 256 + threadIdx.x;
    if (i < BS_TOT * DST) { h[i] = 0.f; sv[i] = 0.f; }
    ov[i] = 0.f;                         // grid is exactly 262144
    if (i < 32768) {
        int k = i >> 8, n = i & 255;
        W1T[i] = (n < 128) ? Al[n * 128 + k] : Wql[(n - 128) * 128 + k];
        CT[i]  = Cl[n * 128 + k];
    }
    if (i < 16384) {
        int k = i >> 7, n = i & 127;
        WoT[i] = Wol[n * 128 + k];
    }
    if (i < 256) B1[i] = (i < 128) ? 0.f : bql[i - 128];
    if (i < 16) cnts[i] = 0;             // cnt1[8], cnt2[8]
}

// ======================= time-mean =======================
__global__ void mean_k(const float* __restrict__ outs, float* __restrict__ ti) {
    int i = blockIdx.x * 256 + threadIdx.x;
    float s = 0.f;
#pragma unroll
    for (int t = 0; t < TSTEPS; ++t) s += outs[t * NE + i];
    ti[i] = s * 0.125f;
}

// ======================= generic fp32 GEMM (plain, +bias) =======================
// C[M,N] = A[M,K] @ W[N,K]^T (+bias). Ascending-k accumulation (bit-stable).
template <int BM, int BN, int BK, int TM, int TN>
__global__ __launch_bounds__((BM / TM) * (BN / TN))
void gemm_k(const float* __restrict__ Amat, const float* __restrict__ Wmat,
            const float* __restrict__ bias, float* __restrict__ outp,
            int M, int N, int K) {
    constexpr int NT  = (BM / TM) * (BN / TN);
    constexpr int NXT = BN / TN;
    __shared__ float As[BK][BM + 4];
    __shared__ float Bs[BK][BN + 4];
    const int tid = threadIdx.x;
    const int n0 = blockIdx.x * BN, m0 = blockIdx.y * BM;
    const int tx = tid % NXT, ty = tid / NXT;
    float acc[TM][TN] = {};

    for (int k0 = 0; k0 < K; k0 += BK) {
#pragma unroll
        for (int i = 0; i < (BM * BK) / NT; ++i) {
            int idx = i * NT + tid;
            int kk = idx % BK, mm = idx / BK;
            As[kk][mm] = Amat[(size_t)(m0 + mm) * K + k0 + kk];
        }
#pragma unroll
        for (int i = 0; i < (BN * BK) / NT; ++i) {
            int idx = i * NT + tid;
            int kk = idx % BK, nn = idx / BK;
            Bs[kk][nn] = Wmat[(size_t)(n0 + nn) * K + k0 + kk];
        }
        __syncthreads();
#pragma unroll
        for (int kk = 0; kk < BK; ++kk) {
            float a[TM], b[TN];
#pragma unroll
            for (int i = 0; i < TM; ++i) a[i] = As[kk][ty * TM + i];
#pragma unroll
            for (int j = 0; j < TN; ++j) b[j] = Bs[kk][tx * TN + j];
#pragma unroll
            for (int i = 0; i < TM; ++i)
#pragma unroll
                for (int j = 0; j < TN; ++j) acc[i][j] += a[i] * b[j];
        }
        __syncthreads();
    }
#pragma unroll
    for (int i = 0; i < TM; ++i) {
        int mr = m0 + ty * TM + i;
#pragma unroll
        for (int j = 0; j < TN; ++j) {
            int nc = n0 + tx * TN + j;
            float x = acc[i][j];
            if (bias) x += bias[nc];
            outp[(size_t)mr * N + nc] = x;
        }
    }
}

// ======================= fused SNN time step =======================
// One kernel per (layer, t). 256 blocks x 256 threads; block owns 4 rows.
// Phases: thr-recompute | load h | stq (sparse) | scores | softmax | PV |
//         Wo+LIF1 | C (sparse) + LIF2.  All dot products ascending-k.
__global__ __launch_bounds__(256) void step_k(
    const float* __restrict__ kvt,         // [1024][256] k | v
    const float* __restrict__ W1T,         // [128][256]
    const float* __restrict__ B1,          // [256]
    const float* __restrict__ WoT,         // [128][128]
    const float* __restrict__ CT,          // [128][256]
    const float* __restrict__ bo,          // [128]
    float* __restrict__ h,                 // [1024][128] spikes (in/out)
    float* __restrict__ sv,                // [1024][128]
    float* __restrict__ ov,                // [1024][256]
    float* __restrict__ outs_t,            // [1024][256] spikes out (this t)
    int* __restrict__ cnt1, int* __restrict__ cnt2, int t)
{
    __shared__ float s_sT[4 * 4100];       // [h][key][4 rows] (+pad)
    __shared__ float stq_s[4 * 260];       // [r][256] st|q
    __shared__ float att_s[4 * 132];       // [r][128]
    __shared__ float hs_s[4 * 128];        // [r][128] spikes
    __shared__ float red_s[16 * 33];
    __shared__ float mrow_s[16], linv_s[16];
    __shared__ unsigned long long umh_s[4][2];
    __shared__ unsigned long long um_s[2];
    __shared__ float thr_s[2];

    const int tid = threadIdx.x;
    const int m0 = blockIdx.x * 4;

    // ---- phase 0: recompute thresholds from per-step spike counts ----
    if (tid == 0) {
        float ts = 1.0f, to = 1.0f;
        for (int i = 0; i < t; ++i) {
            float e1 = (float)cnt1[i] * (1.f / 131072.f) - 0.02f;
            ts = fmaxf(ts + 0.1f * e1, 0.5f);
            float e2 = (float)cnt2[i] * (1.f / 262144.f) - 0.02f;
            to = fmaxf(to + 0.1f * e2, 0.5f);
        }
        thr_s[0] = ts; thr_s[1] = to;
    }
    // ---- load previous spikes ----
#pragma unroll
    for (int i = 0; i < 2; ++i) {
        int idx = i * 256 + tid;           // [4][128] contiguous
        hs_s[idx] = h[m0 * DST + idx];
    }
    __syncthreads();
    {   // ballot per row (wave w -> row w)
        int w = tid >> 6, l = tid & 63;
        unsigned long long b0 = __ballot(hs_s[w * 128 + l] != 0.f);
        unsigned long long b1 = __ballot(hs_s[w * 128 + 64 + l] != 0.f);
        if (l == 0) { umh_s[w][0] = b0; umh_s[w][1] = b1; }
    }
    __syncthreads();
    if (tid == 0) {
        um_s[0] = umh_s[0][0] | umh_s[1][0] | umh_s[2][0] | umh_s[3][0];
        um_s[1] = umh_s[0][1] | umh_s[1][1] | umh_s[2][1] | umh_s[3][1];
    }
    __syncthreads();

    // ---- phase 1: stq[r][n] = sum_k h[r][k]*W1T[k][n] + B1[n]  (sparse, exact)
    {
        int n = tid;
        float a0 = 0.f, a1 = 0.f, a2 = 0.f, a3 = 0.f;
        unsigned long long u = um_s[0];
        while (u) {
            int k = __builtin_ctzll(u); u &= u - 1;
            float w = W1T[(k << 8) + n];
            a0 += hs_s[k] * w;       a1 += hs_s[128 + k] * w;
            a2 += hs_s[256 + k] * w; a3 += hs_s[384 + k] * w;
        }
        u = um_s[1];
        while (u) {
            int kk = __builtin_ctzll(u); u &= u - 1;
            int k = 64 + kk;
            float w = W1T[(k << 8) + n];
            a0 += hs_s[k] * w;       a1 += hs_s[128 + k] * w;
            a2 += hs_s[256 + k] * w; a3 += hs_s[384 + k] * w;
        }
        stq_s[0 * 260 + n] = a0 + B1[n];
        stq_s[1 * 260 + n] = a1 + B1[n];
        stq_s[2 * 260 + n] = a2 + B1[n];
        stq_s[3 * 260 + n] = a3 + B1[n];
    }
    __syncthreads();

    // ---- phase 2: scores. lane=(key16,row), 4 waves cover 64 keys/chunk ----
    {
        const int l = tid & 63, w = tid >> 6;
        const int r = l & 3, key16 = l >> 2;
        const float4* kv4 = (const float4*)kvt;
        for (int hh = 0; hh < 4; ++hh) {
            float q[32];
#pragma unroll
            for (int d = 0; d < 32; ++d) q[d] = stq_s[r * 260 + 128 + hh * 32 + d];
            for (int c = 0; c < 16; ++c) {
                int key = c * 64 + w * 16 + key16;
                const float4* kp = kv4 + (size_t)key * 64 + hh * 8;
                float s = 0.f;
#pragma unroll
                for (int dq = 0; dq < 8; ++dq) {
                    float4 kq = kp[dq];
                    s += q[dq * 4 + 0] * kq.x;
                    s += q[dq * 4 + 1] * kq.y;
                    s += q[dq * 4 + 2] * kq.z;
                    s += q[dq * 4 + 3] * kq.w;
                }
                s_sT[hh * 4100 + key * 4 + r] = s * SCALEF;
            }
        }
    }
    __syncthreads();

    // ---- softmax (two-pass, round-1 reduction order), rh = h*4 + r ----
    {
        const int lg = tid & 31;
#pragma unroll
        for (int pass = 0; pass < 2; ++pass) {
            int rh = (tid >> 5) + 8 * pass;
            int hh = rh >> 2, rr = rh & 3;
            float mx = -1e30f;
            for (int jj = 0; jj < 32; ++jj)
                mx = fmaxf(mx, s_sT[hh * 4100 + (lg + 32 * jj) * 4 + rr]);
            red_s[rh * 33 + lg] = mx;
        }
        __syncthreads();
        if (tid < 16) {
            float m = red_s[tid * 33 + 0];
            for (int j = 1; j < 32; ++j) m = fmaxf(m, red_s[tid * 33 + j]);
            mrow_s[tid] = m;
        }
        __syncthreads();
#pragma unroll
        for (int pass = 0; pass < 2; ++pass) {
            int rh = (tid >> 5) + 8 * pass;
            int hh = rh >> 2, rr = rh & 3;
            float m = mrow_s[rh];
            float ls = 0.f;
            for (int jj = 0; jj < 32; ++jj) {
                int a = hh * 4100 + (lg + 32 * jj) * 4 + rr;
                float p = expf(s_sT[a] - m);
                s_sT[a] = p;
                ls += p;
            }
            red_s[rh * 33 + lg] = ls;
        }
        __syncthreads();
        if (tid < 16) {
            float lsum = 0.f;
            for (int j = 0; j < 32; ++j) lsum += red_s[tid * 33 + j];
            linv_s[tid] = 1.0f / lsum;
        }
    }
    __syncthreads();

    // ---- PV: 2 waves; lane=(row, d-quad); v from global (coalesced) ----
    if (tid < 128) {
        int w2 = tid >> 6, l = tid & 63;
        int r = l >> 4, d4 = w2 * 16 + (l & 15);
        int hh = d4 >> 3;
        const float4* kv4 = (const float4*)kvt;
        float ax = 0.f, ay = 0.f, az = 0.f, aw = 0.f;
        for (int c = 0; c < 16; ++c) {
#pragma unroll 8
            for (int j = 0; j < 64; ++j) {
                int key = c * 64 + j;
                float p = s_sT[hh * 4100 + key * 4 + r];
                float4 v = kv4[(size_t)key * 64 + 32 + d4];
                ax += p * v.x; ay += p * v.y; az += p * v.z; aw += p * v.w;
            }
        }
        float li = linv_s[hh * 4 + r];
        att_s[r * 132 + d4 * 4 + 0] = ax * li;
        att_s[r * 132 + d4 * 4 + 1] = ay * li;
        att_s[r * 132 + d4 * 4 + 2] = az * li;
        att_s[r * 132 + d4 * 4 + 3] = aw * li;
    }
    __syncthreads();

    // ---- phase 3: upd = (att@WoT + bo) + st -> LIF1 ----
    {
        int n = tid & 127, r0 = tid >> 7;   // rows r0 and r0+2
        float b0 = 0.f, b1 = 0.f;
        for (int k = 0; k < 128; ++k) {
            float w = WoT[(k << 7) + n];
            b0 += att_s[r0 * 132 + k] * w;
            b1 += att_s[(r0 + 2) * 132 + k] * w;
        }
        float ts = thr_s[0];
        float x0 = b0; x0 += bo[n]; x0 += stq_s[r0 * 260 + n];
        float v0 = sv[(m0 + r0) * DST + n];
        float vp0 = v0 * DECAYF + x0;
        float sp0 = (vp0 - ts >= 0.f) ? 1.f : 0.f;
        h[(m0 + r0) * DST + n]  = sp0;
        sv[(m0 + r0) * DST + n] = vp0 * (1.f - sp0);
        hs_s[r0 * 128 + n] = sp0;

        float x1 = b1; x1 += bo[n]; x1 += stq_s[(r0 + 2) * 260 + n];
        float v1 = sv[(m0 + r0 + 2) * DST + n];
        float vp1 = v1 * DECAYF + x1;
        float sp1 = (vp1 - ts >= 0.f) ? 1.f : 0.f;
        h[(m0 + r0 + 2) * DST + n]  = sp1;
        sv[(m0 + r0 + 2) * DST + n] = vp1 * (1.f - sp1);
        hs_s[(r0 + 2) * 128 + n] = sp1;

        unsigned long long ba = __ballot(sp0 != 0.f);
        unsigned long long bb = __ballot(sp1 != 0.f);
        int w = tid >> 6, l = tid & 63;
        if (l == 0) {
            int half = w & 1;
            umh_s[r0][half]     = ba;
            umh_s[r0 + 2][half] = bb;
            atomicAdd(&cnt1[t], __popcll(ba) + __popcll(bb));
        }
    }
    __syncthreads();
    if (tid == 0) {
        um_s[0] = umh_s[0][0] | umh_s[1][0] | umh_s[2][0] | umh_s[3][0];
        um_s[1] = umh_s[0][1] | umh_s[1][1] | umh_s[2][1] | umh_s[3][1];
    }
    __syncthreads();

    // ---- phase 4: out_pot = h2@CT -> LIF2 -> outs ----
    {
        int n = tid;
        float a0 = 0.f, a1 = 0.f, a2 = 0.f, a3 = 0.f;
        unsigned long long u = um_s[0];
        while (u) {
            int k = __builtin_ctzll(u); u &= u - 1;
            float w = CT[(k << 8) + n];
            a0 += hs_s[k] * w;       a1 += hs_s[128 + k] * w;
            a2 += hs_s[256 + k] * w; a3 += hs_s[384 + k] * w;
        }
        u = um_s[1];
        while (u) {
            int kk = __builtin_ctzll(u); u &= u - 1;
            int k = 64 + kk;
            float w = CT[(k << 8) + n];
            a0 += hs_s[k] * w;       a1 += hs_s[128 + k] * w;
            a2 += hs_s[256 + k] * w; a3 += hs_s[384 + k] * w;
        }
        float to = thr_s[1];
        float sp[4];
        float accs[4] = {a0, a1, a2, a3};
#pragma unroll
        for (int r = 0; r < 4; ++r) {
            float vo = ov[(m0 + r) * DM + n];
            float x = accs[r];
            float vp = vo * DECAYF + x;
            float s = (vp - to >= 0.f) ? 1.f : 0.f;
            sp[r] = s;
            outs_t[(size_t)(m0 + r) * DM + n] = s;
            ov[(m0 + r) * DM + n] = vp * (1.f - s);
        }
        unsigned long long c0 = __ballot(sp[0] != 0.f);
        unsigned long long c1 = __ballot(sp[1] != 0.f);
        unsigned long long c2 = __ballot(sp[2] != 0.f);
        unsigned long long c3 = __ballot(sp[3] != 0.f);
        if ((tid & 63) == 0)
            atomicAdd(&cnt2[t], __popcll(c0) + __popcll(c1) + __popcll(c2) + __popcll(c3));
    }
}

// ======================= host =======================
extern "C" void kernel_launch(void* const* d_in, const int* in_sizes, int n_in,
                              void* d_out, int out_size, void* d_ws, size_t ws_size,
                              hipStream_t stream) {
    (void)in_sizes; (void)n_in; (void)out_size; (void)ws_size;
    const int*   ids  = (const int*)d_in[0];
    const float* emb  = (const float*)d_in[1];
    const float* Aw   = (const float*)d_in[2];
    const float* Cw   = (const float*)d_in[3];
    const float* Wq   = (const float*)d_in[4];
    const float* bq   = (const float*)d_in[5];
    const float* Wkv  = (const float*)d_in[6];
    const float* bkv  = (const float*)d_in[7];
    const float* Wo   = (const float*)d_in[8];
    const float* bo   = (const float*)d_in[9];
    const float* Wout = (const float*)d_in[10];
    const float* bout = (const float*)d_in[11];
    float* out = (float*)d_out;
    float* ws  = (float*)d_ws;

    float* tok  = ws;                     // 262144
    float* bufA = tok  + NE;              // 8*262144
    float* bufB = bufA + 8 * NE;          // 8*262144
    float* kvb  = bufB + 8 * NE;          // 8*262144
    float* hbuf = kvb  + 8 * NE;          // 131072
    float* sv   = hbuf + BS_TOT * DST;    // 131072
    float* ov   = sv   + BS_TOT * DST;    // 262144
    float* ti   = ov   + NE;              // 262144
    float* W1T  = ti   + NE;              // 32768
    float* B1   = W1T  + 32768;           // 256
    float* WoT  = B1   + 256;             // 16384
    float* CT   = WoT  + 16384;           // 32768
    int*   cnts = (int*)(CT + 32768);     // cnt1[8], cnt2[8]

    embed_k<<<dim3(1024), dim3(256), 0, stream>>>(ids, emb, tok);

    for (int l = 0; l < 2; ++l) {
        const float* Al   = Aw  + l * 16384;
        const float* Cl   = Cw  + l * 32768;
        const float* Wql  = Wq  + l * 16384;
        const float* bql  = bq  + l * 128;
        const float* Wkvl = Wkv + l * 65536;
        const float* bkvl = bkv + l * 256;
        const float* Wol  = Wo  + l * 16384;
        const float* bol  = bo  + l * 128;
        const float* xin  = (l == 0) ? tok : bufA;
        float* outs       = (l == 0) ? bufA : bufB;
        int Mkv           = (l == 0) ? BS_TOT : 8 * BS_TOT;

        init_k<<<dim3(1024), dim3(256), 0, stream>>>(hbuf, sv, ov, W1T, B1, WoT, CT,
                                                     Al, Wql, bql, Wol, Cl, cnts);

        // kv for the whole layer (identical math/order to round-1)
        gemm_k<32, 32, 16, 4, 4><<<dim3(256 / 32, Mkv / 32), dim3(64), 0, stream>>>(
            xin, Wkvl, bkvl, kvb, Mkv, 256, 256);

        for (int t = 0; t < TSTEPS; ++t) {
            const float* kvt = (l == 0) ? kvb : kvb + (size_t)t * NE;
            step_k<<<dim3(256), dim3(256), 0, stream>>>(
                kvt, W1T, B1, WoT, CT, bol,
                hbuf, sv, ov, outs + (size_t)t * NE,
                cnts, cnts + 8, t);
        }
    }

    mean_k<<<dim3(1024), dim3(256), 0, stream>>>(bufB, ti);

    // logits = ti @ Wout^T + bout
    gemm_k<128, 128, 16, 8, 8><<<dim3(32000 / 128, BS_TOT / 128), dim3(256), 0, stream>>>(
        ti, Wout, bout, out, BS_TOT, 32000, 256);
}